// Round 2
// baseline (917.313 us; speedup 1.0000x reference)
//
#include <hip/hip_runtime.h>

#define N_NODES 50000
#define N_EDGES 800000
#define DIN 256
#define DHID 128
#define DOUT 128

// ---------------- Kernel 1: h = x @ W1 (f32), e_src = h.att_src, e_dst = h.att_dst
// 4 rows per block, 128 threads (one per hid column).
__global__ __launch_bounds__(128) void gemm1_kernel(
    const float* __restrict__ x,
    const float* __restrict__ W1,
    const float* __restrict__ att_src,
    const float* __restrict__ att_dst,
    float* __restrict__ h,
    float* __restrict__ es,
    float* __restrict__ ed)
{
    const int tid  = threadIdx.x;        // 0..127 = hid column
    const int row0 = blockIdx.x * 4;

    __shared__ float xs[4 * DIN];
    __shared__ float s2[16];

    // stage 4 rows of x (4*256 f32 = 4KB) via float4
    {
        const float4* xg = (const float4*)(x + (size_t)row0 * DIN);
        float4* xs4 = (float4*)xs;
        #pragma unroll
        for (int i = tid; i < 4 * DIN / 4; i += 128)
            xs4[i] = xg[i];
    }
    __syncthreads();

    float acc0 = 0.f, acc1 = 0.f, acc2 = 0.f, acc3 = 0.f;
    #pragma unroll 4
    for (int k = 0; k < DIN; ++k) {
        float w = W1[k * DHID + tid];    // coalesced, 128KB → L2-hot
        acc0 += xs[k          ] * w;
        acc1 += xs[DIN     + k] * w;
        acc2 += xs[2 * DIN + k] * w;
        acc3 += xs[3 * DIN + k] * w;
    }
    h[(size_t)(row0 + 0) * DHID + tid] = acc0;
    h[(size_t)(row0 + 1) * DHID + tid] = acc1;
    h[(size_t)(row0 + 2) * DHID + tid] = acc2;
    h[(size_t)(row0 + 3) * DHID + tid] = acc3;

    const float as = att_src[tid];
    const float ad = att_dst[tid];
    float v[8] = { acc0 * as, acc1 * as, acc2 * as, acc3 * as,
                   acc0 * ad, acc1 * ad, acc2 * ad, acc3 * ad };

    // wave64 shuffle reduce, then combine the 2 waves through LDS
    #pragma unroll
    for (int off = 32; off; off >>= 1)
        #pragma unroll
        for (int j = 0; j < 8; ++j)
            v[j] += __shfl_down(v[j], off);

    if ((tid & 63) == 0) {
        const int w = tid >> 6;
        #pragma unroll
        for (int j = 0; j < 8; ++j) s2[w * 8 + j] = v[j];
    }
    __syncthreads();
    if (tid < 8) {
        float r = s2[tid] + s2[8 + tid];
        if (tid < 4) es[row0 + tid]       = r;
        else         ed[row0 + (tid - 4)] = r;
    }
}

// ---------------- Kernel 2: per-edge ex = exp(sigmoid(es[src]+ed[dst])), denom scatter-sum.
// (segment-max cancels algebraically in softmax; alpha in (0,1) so exp(alpha) in (1,e) — safe)
__global__ __launch_bounds__(256) void edge_logits_kernel(
    const int* __restrict__ ei,
    const float* __restrict__ es,
    const float* __restrict__ ed,
    float* __restrict__ exw,
    float* __restrict__ denom)
{
    int e = blockIdx.x * 256 + threadIdx.x;
    if (e >= N_EDGES) return;
    int s = ei[e];
    int d = ei[N_EDGES + e];
    float a  = es[s] + ed[d];
    float sg = 1.f / (1.f + __expf(-a));
    float ex = __expf(sg);
    exw[e] = ex;
    atomicAdd(&denom[d], ex);
}

// ---------------- Kernel 3: agg[dst] += (ex/denom[dst]) * h[src]  (one wave per edge)
__global__ __launch_bounds__(256) void aggregate_kernel(
    const int* __restrict__ ei,
    const float* __restrict__ h,
    const float* __restrict__ exw,
    const float* __restrict__ denom,
    float* __restrict__ agg)
{
    int wid  = (blockIdx.x * 256 + threadIdx.x) >> 6;   // edge id
    int lane = threadIdx.x & 63;
    if (wid >= N_EDGES) return;
    int s = ei[wid];
    int d = ei[N_EDGES + wid];
    float w = exw[wid] / denom[d];                      // broadcast reads
    float2 hv = ((const float2*)(h + (size_t)s * DHID))[lane];
    atomicAdd(&agg[(size_t)d * DHID + 2 * lane    ], w * hv.x);
    atomicAdd(&agg[(size_t)d * DHID + 2 * lane + 1], w * hv.y);
}

// ---------------- Kernel 4: out = elu(agg) @ W2, 4 rows per block
__global__ __launch_bounds__(128) void out_gemm_kernel(
    const float* __restrict__ agg,
    const float* __restrict__ W2,
    float* __restrict__ out)
{
    const int tid  = threadIdx.x;        // 0..127 = out column
    const int row0 = blockIdx.x * 4;

    __shared__ float h1[4 * DHID];

    #pragma unroll
    for (int r = 0; r < 4; ++r) {
        float vv = agg[(size_t)(row0 + r) * DHID + tid];
        h1[r * DHID + tid] = vv > 0.f ? vv : (__expf(vv) - 1.f);   // elu
    }
    __syncthreads();

    float a0 = 0.f, a1 = 0.f, a2 = 0.f, a3 = 0.f;
    #pragma unroll 4
    for (int k = 0; k < DHID; ++k) {
        float w = W2[k * DOUT + tid];    // 64KB, L2-hot
        a0 += h1[k           ] * w;
        a1 += h1[DHID     + k] * w;
        a2 += h1[2 * DHID + k] * w;
        a3 += h1[3 * DHID + k] * w;
    }
    out[(size_t)(row0 + 0) * DOUT + tid] = a0;
    out[(size_t)(row0 + 1) * DOUT + tid] = a1;
    out[(size_t)(row0 + 2) * DOUT + tid] = a2;
    out[(size_t)(row0 + 3) * DOUT + tid] = a3;
}

extern "C" void kernel_launch(void* const* d_in, const int* in_sizes, int n_in,
                              void* d_out, int out_size, void* d_ws, size_t ws_size,
                              hipStream_t stream)
{
    const float* x    = (const float*)d_in[0];
    const int*   ei   = (const int*)d_in[1];
    const float* W1   = (const float*)d_in[2];
    const float* asrc = (const float*)d_in[3];
    const float* adst = (const float*)d_in[4];
    const float* W2   = (const float*)d_in[5];
    float*       out  = (float*)d_out;

    // workspace layout (f32), total ~55 MB
    float* h     = (float*)d_ws;                         // N*128
    float* es    = h   + (size_t)N_NODES * DHID;         // N
    float* ed    = es  + N_NODES;                        // N
    float* exw   = ed  + N_NODES;                        // E
    float* denom = exw + N_EDGES;                        // N
    float* agg   = denom + N_NODES;                      // N*128  (contiguous after denom)

    // zero denom + agg in one shot (ws is re-poisoned 0xAA before every call)
    hipMemsetAsync(denom, 0, sizeof(float) * ((size_t)N_NODES + (size_t)N_NODES * DHID),
                   stream);

    gemm1_kernel<<<N_NODES / 4, 128, 0, stream>>>(x, W1, asrc, adst, h, es, ed);
    edge_logits_kernel<<<(N_EDGES + 255) / 256, 256, 0, stream>>>(ei, es, ed, exw, denom);
    aggregate_kernel<<<(N_EDGES * 64 + 255) / 256, 256, 0, stream>>>(ei, h, exw, denom, agg);
    out_gemm_kernel<<<N_NODES / 4, 128, 0, stream>>>(agg, W2, out);
}

// Round 3
// 444.310 us; speedup vs baseline: 2.0646x; 2.0646x over previous
//
#include <hip/hip_runtime.h>

#define N_NODES 50000
#define N_EDGES 800000
#define DIN 256
#define DHID 128
#define DOUT 128

// ---------------- Kernel 1: h = x @ W1 (f32), e_src = h.att_src, e_dst = h.att_dst
__global__ __launch_bounds__(128) void gemm1_kernel(
    const float* __restrict__ x,
    const float* __restrict__ W1,
    const float* __restrict__ att_src,
    const float* __restrict__ att_dst,
    float* __restrict__ h,
    float* __restrict__ es,
    float* __restrict__ ed)
{
    const int tid  = threadIdx.x;        // 0..127 = hid column
    const int row0 = blockIdx.x * 4;

    __shared__ float xs[4 * DIN];
    __shared__ float s2[16];

    {
        const float4* xg = (const float4*)(x + (size_t)row0 * DIN);
        float4* xs4 = (float4*)xs;
        #pragma unroll
        for (int i = tid; i < 4 * DIN / 4; i += 128)
            xs4[i] = xg[i];
    }
    __syncthreads();

    float acc0 = 0.f, acc1 = 0.f, acc2 = 0.f, acc3 = 0.f;
    #pragma unroll 4
    for (int k = 0; k < DIN; ++k) {
        float w = W1[k * DHID + tid];    // coalesced, 128KB -> L2-hot
        acc0 += xs[k          ] * w;
        acc1 += xs[DIN     + k] * w;
        acc2 += xs[2 * DIN + k] * w;
        acc3 += xs[3 * DIN + k] * w;
    }
    h[(size_t)(row0 + 0) * DHID + tid] = acc0;
    h[(size_t)(row0 + 1) * DHID + tid] = acc1;
    h[(size_t)(row0 + 2) * DHID + tid] = acc2;
    h[(size_t)(row0 + 3) * DHID + tid] = acc3;

    const float as = att_src[tid];
    const float ad = att_dst[tid];
    float v[8] = { acc0 * as, acc1 * as, acc2 * as, acc3 * as,
                   acc0 * ad, acc1 * ad, acc2 * ad, acc3 * ad };

    #pragma unroll
    for (int off = 32; off; off >>= 1)
        #pragma unroll
        for (int j = 0; j < 8; ++j)
            v[j] += __shfl_down(v[j], off);

    if ((tid & 63) == 0) {
        const int w = tid >> 6;
        #pragma unroll
        for (int j = 0; j < 8; ++j) s2[w * 8 + j] = v[j];
    }
    __syncthreads();
    if (tid < 8) {
        float r = s2[tid] + s2[8 + tid];
        if (tid < 4) es[row0 + tid]       = r;
        else         ed[row0 + (tid - 4)] = r;
    }
}

// ---------------- Kernel 2: histogram of dst degrees (int atomics, 50K counters)
__global__ __launch_bounds__(256) void hist_kernel(
    const int* __restrict__ ei,
    int* __restrict__ count)
{
    int e = blockIdx.x * 256 + threadIdx.x;
    if (e >= N_EDGES) return;
    atomicAdd(&count[ei[N_EDGES + e]], 1);
}

// ---------------- Kernel 3: exclusive scan of count -> offset; zero count (reuse as cursor).
// Single block, 1024 threads, ~49 elements per thread.
__global__ __launch_bounds__(1024) void scan_kernel(
    int* __restrict__ count,
    int* __restrict__ offset)
{
    __shared__ int partial[1024];
    const int C = (N_NODES + 1023) / 1024;   // 49
    const int t = threadIdx.x;
    const int base = t * C;

    int sum = 0;
    int local[49];
    #pragma unroll
    for (int i = 0; i < C; ++i) {
        int idx = base + i;
        local[i] = (idx < N_NODES) ? count[idx] : 0;
        sum += local[i];
    }
    partial[t] = sum;
    __syncthreads();

    // Hillis-Steele inclusive scan over 1024 partials
    #pragma unroll
    for (int off = 1; off < 1024; off <<= 1) {
        int v = (t >= off) ? partial[t - off] : 0;
        __syncthreads();
        partial[t] += v;
        __syncthreads();
    }
    int run = (t == 0) ? 0 : partial[t - 1];

    #pragma unroll
    for (int i = 0; i < C; ++i) {
        int idx = base + i;
        if (idx < N_NODES) {
            offset[idx] = run;
            run += local[i];
            count[idx] = 0;          // becomes scatter cursor; K5 restores it to deg
        }
    }
}

// ---------------- Kernel 4: scatter edge srcs into CSR order
__global__ __launch_bounds__(256) void scatter_kernel(
    const int* __restrict__ ei,
    const int* __restrict__ offset,
    int* __restrict__ count,          // cursor; ends back at deg
    int* __restrict__ sortedSrc)
{
    int e = blockIdx.x * 256 + threadIdx.x;
    if (e >= N_EDGES) return;
    int s = ei[e];
    int d = ei[N_EDGES + e];
    int pos = offset[d] + atomicAdd(&count[d], 1);
    sortedSrc[pos] = s;
}

// ---------------- Kernel 5: gather-aggregate, one wave per dst node, no f32 atomics.
// agg[d] = (sum_e w_e * h[src_e]) / (sum_e w_e),  w_e = exp(sigmoid(es[s]+ed[d]))
__global__ __launch_bounds__(256) void agg_kernel(
    const int* __restrict__ sortedSrc,
    const int* __restrict__ offset,
    const int* __restrict__ count,
    const float* __restrict__ es,
    const float* __restrict__ ed,
    const float* __restrict__ h,
    float* __restrict__ agg)
{
    int node = (blockIdx.x * 256 + threadIdx.x) >> 6;
    int lane = threadIdx.x & 63;
    if (node >= N_NODES) return;

    int off = offset[node];
    int deg = count[node];
    float edn = ed[node];

    float2 acc = make_float2(0.f, 0.f);
    float wsum = 0.f;

    #pragma unroll 2
    for (int i = 0; i < deg; ++i) {
        int s = sortedSrc[off + i];
        float a  = es[s] + edn;
        float sg = 1.f / (1.f + __expf(-a));
        float w  = __expf(sg);
        float2 hv = ((const float2*)(h + (size_t)s * DHID))[lane];
        acc.x += w * hv.x;
        acc.y += w * hv.y;
        wsum  += w;
    }
    float inv = (deg > 0) ? 1.f / wsum : 0.f;
    ((float2*)(agg + (size_t)node * DHID))[lane] = make_float2(acc.x * inv, acc.y * inv);
}

// ---------------- Kernel 6: out = elu(agg) @ W2, 4 rows per block
__global__ __launch_bounds__(128) void out_gemm_kernel(
    const float* __restrict__ agg,
    const float* __restrict__ W2,
    float* __restrict__ out)
{
    const int tid  = threadIdx.x;        // 0..127 = out column
    const int row0 = blockIdx.x * 4;

    __shared__ float h1[4 * DHID];

    #pragma unroll
    for (int r = 0; r < 4; ++r) {
        float vv = agg[(size_t)(row0 + r) * DHID + tid];
        h1[r * DHID + tid] = vv > 0.f ? vv : (__expf(vv) - 1.f);   // elu
    }
    __syncthreads();

    float a0 = 0.f, a1 = 0.f, a2 = 0.f, a3 = 0.f;
    #pragma unroll 4
    for (int k = 0; k < DHID; ++k) {
        float w = W2[k * DOUT + tid];    // 64KB, L2-hot
        a0 += h1[k           ] * w;
        a1 += h1[DHID     + k] * w;
        a2 += h1[2 * DHID + k] * w;
        a3 += h1[3 * DHID + k] * w;
    }
    out[(size_t)(row0 + 0) * DOUT + tid] = a0;
    out[(size_t)(row0 + 1) * DOUT + tid] = a1;
    out[(size_t)(row0 + 2) * DOUT + tid] = a2;
    out[(size_t)(row0 + 3) * DOUT + tid] = a3;
}

extern "C" void kernel_launch(void* const* d_in, const int* in_sizes, int n_in,
                              void* d_out, int out_size, void* d_ws, size_t ws_size,
                              hipStream_t stream)
{
    const float* x    = (const float*)d_in[0];
    const int*   ei   = (const int*)d_in[1];
    const float* W1   = (const float*)d_in[2];
    const float* asrc = (const float*)d_in[3];
    const float* adst = (const float*)d_in[4];
    const float* W2   = (const float*)d_in[5];
    float*       out  = (float*)d_out;

    // workspace layout (~55 MB)
    float* h         = (float*)d_ws;                       // N*128 f32
    float* es        = h  + (size_t)N_NODES * DHID;        // N
    float* ed        = es + N_NODES;                       // N
    int*   count     = (int*)(ed + N_NODES);               // N
    int*   offset    = count + N_NODES;                    // N
    int*   sortedSrc = offset + N_NODES;                   // E
    float* agg       = (float*)(sortedSrc + N_EDGES);      // N*128 f32

    // only the histogram counters need zeroing (ws re-poisoned 0xAA each call)
    hipMemsetAsync(count, 0, sizeof(int) * N_NODES, stream);

    gemm1_kernel<<<N_NODES / 4, 128, 0, stream>>>(x, W1, asrc, adst, h, es, ed);
    hist_kernel<<<(N_EDGES + 255) / 256, 256, 0, stream>>>(ei, count);
    scan_kernel<<<1, 1024, 0, stream>>>(count, offset);
    scatter_kernel<<<(N_EDGES + 255) / 256, 256, 0, stream>>>(ei, offset, count, sortedSrc);
    agg_kernel<<<(N_NODES * 64 + 255) / 256, 256, 0, stream>>>(
        sortedSrc, offset, count, es, ed, h, agg);
    out_gemm_kernel<<<N_NODES / 4, 128, 0, stream>>>(agg, W2, out);
}

// Round 4
// 390.352 us; speedup vs baseline: 2.3500x; 1.1382x over previous
//
#include <hip/hip_runtime.h>
#include <hip/hip_bf16.h>

#define N_NODES 50000
#define N_EDGES 800000
#define DIN 256
#define DHID 128
#define DOUT 128

typedef __attribute__((ext_vector_type(8))) short bf16x8;
typedef __attribute__((ext_vector_type(4))) float f32x4;

__device__ inline unsigned short f2b(float f) {
    __hip_bfloat16 b = __float2bfloat16(f);
    return *reinterpret_cast<unsigned short*>(&b);
}

// ---------------- cast x (f32) -> xb (bf16), 4 elems/thread
__global__ __launch_bounds__(256) void convx_kernel(
    const float* __restrict__ x, unsigned short* __restrict__ xb)
{
    int i = (blockIdx.x * 256 + threadIdx.x) * 4;
    float4 v = *(const float4*)(x + i);
    ushort4 o;
    o.x = f2b(v.x); o.y = f2b(v.y); o.z = f2b(v.z); o.w = f2b(v.w);
    *(ushort4*)(xb + i) = o;
}

// ---------------- W1t[n*256+k] = bf16(W1[k*128+n])   (32768 elems)
__global__ __launch_bounds__(256) void convW1_kernel(
    const float* __restrict__ W1, unsigned short* __restrict__ W1t)
{
    int i = blockIdx.x * 256 + threadIdx.x;   // i = n*256 + k
    int n = i >> 8, k = i & 255;
    W1t[i] = f2b(W1[k * DHID + n]);
}

// ---------------- W2t[n*128+k] = bf16(W2[k*128+n])   (16384 elems)
__global__ __launch_bounds__(256) void convW2_kernel(
    const float* __restrict__ W2, unsigned short* __restrict__ W2t)
{
    int i = blockIdx.x * 256 + threadIdx.x;   // i = n*128 + k
    int n = i >> 7, k = i & 127;
    W2t[i] = f2b(W2[k * DOUT + n]);
}

// ---------------- gemm1: hb = bf16( xb @ W1t^T ), MFMA 16x16x32, no LDS.
// 4 waves/block, 16 rows/wave, 128 cols, K=256.
__global__ __launch_bounds__(256) void gemm1_mfma(
    const unsigned short* __restrict__ xb,
    const unsigned short* __restrict__ W1t,
    unsigned short* __restrict__ hb)
{
    const int wave = threadIdx.x >> 6, lane = threadIdx.x & 63;
    const int row0 = blockIdx.x * 64 + wave * 16;
    const int m = lane & 15, q = lane >> 4;

    int r  = row0 + m;
    int rc = (r < N_NODES) ? r : 0;            // clamp; stores guarded below

    f32x4 acc[8];
    #pragma unroll
    for (int t = 0; t < 8; ++t) acc[t] = (f32x4){0.f, 0.f, 0.f, 0.f};

    const short* xp = (const short*)xb + (size_t)rc * DIN + q * 8;
    const short* wp = (const short*)W1t + q * 8;

    #pragma unroll
    for (int kt = 0; kt < 8; ++kt) {
        bf16x8 a = *(const bf16x8*)(xp + kt * 32);
        #pragma unroll
        for (int t = 0; t < 8; ++t) {
            bf16x8 b = *(const bf16x8*)(wp + (size_t)(t * 16 + m) * DIN + kt * 32);
            acc[t] = __builtin_amdgcn_mfma_f32_16x16x32_bf16(a, b, acc[t], 0, 0, 0);
        }
    }

    // C/D layout: row = q*4 + reg, col = t*16 + m
    #pragma unroll
    for (int reg = 0; reg < 4; ++reg) {
        int rr = row0 + q * 4 + reg;
        if (rr < N_NODES) {
            #pragma unroll
            for (int t = 0; t < 8; ++t)
                hb[(size_t)rr * DHID + t * 16 + m] = f2b(acc[t][reg]);
        }
    }
}

// ---------------- es/ed = hb . att_src / att_dst, one wave per row
__global__ __launch_bounds__(256) void edot_kernel(
    const unsigned short* __restrict__ hb,
    const float* __restrict__ att_src,
    const float* __restrict__ att_dst,
    float* __restrict__ es, float* __restrict__ ed)
{
    int row  = (blockIdx.x * 256 + threadIdx.x) >> 6;
    int lane = threadIdx.x & 63;
    if (row >= N_NODES) return;

    unsigned int u = *(const unsigned int*)(hb + (size_t)row * DHID + 2 * lane);
    float h0 = __uint_as_float(u << 16);
    float h1 = __uint_as_float(u & 0xffff0000u);
    float vs = h0 * att_src[2 * lane] + h1 * att_src[2 * lane + 1];
    float vd = h0 * att_dst[2 * lane] + h1 * att_dst[2 * lane + 1];

    #pragma unroll
    for (int off = 32; off; off >>= 1) {
        vs += __shfl_down(vs, off);
        vd += __shfl_down(vd, off);
    }
    if (lane == 0) { es[row] = vs; ed[row] = vd; }
}

// ---------------- histogram of dst degrees
__global__ __launch_bounds__(256) void hist_kernel(
    const int* __restrict__ ei, int* __restrict__ count)
{
    int e = blockIdx.x * 256 + threadIdx.x;
    if (e >= N_EDGES) return;
    atomicAdd(&count[ei[N_EDGES + e]], 1);
}

// ---------------- exclusive scan (single block); zeroes count for cursor reuse
__global__ __launch_bounds__(1024) void scan_kernel(
    int* __restrict__ count, int* __restrict__ offset)
{
    __shared__ int partial[1024];
    const int C = (N_NODES + 1023) / 1024;   // 49
    const int t = threadIdx.x;
    const int base = t * C;

    int sum = 0;
    int local[49];
    #pragma unroll
    for (int i = 0; i < C; ++i) {
        int idx = base + i;
        local[i] = (idx < N_NODES) ? count[idx] : 0;
        sum += local[i];
    }
    partial[t] = sum;
    __syncthreads();

    #pragma unroll
    for (int off = 1; off < 1024; off <<= 1) {
        int v = (t >= off) ? partial[t - off] : 0;
        __syncthreads();
        partial[t] += v;
        __syncthreads();
    }
    int run = (t == 0) ? 0 : partial[t - 1];

    #pragma unroll
    for (int i = 0; i < C; ++i) {
        int idx = base + i;
        if (idx < N_NODES) {
            offset[idx] = run;
            run += local[i];
            count[idx] = 0;
        }
    }
}

// ---------------- scatter edge srcs into CSR order
__global__ __launch_bounds__(256) void scatter_kernel(
    const int* __restrict__ ei, const int* __restrict__ offset,
    int* __restrict__ count, int* __restrict__ sortedSrc)
{
    int e = blockIdx.x * 256 + threadIdx.x;
    if (e >= N_EDGES) return;
    int s = ei[e];
    int d = ei[N_EDGES + e];
    int pos = offset[d] + atomicAdd(&count[d], 1);
    sortedSrc[pos] = s;
}

// ---------------- gather-aggregate, one wave per dst node (bf16 h)
__global__ __launch_bounds__(256) void agg_kernel(
    const int* __restrict__ sortedSrc,
    const int* __restrict__ offset,
    const int* __restrict__ count,
    const float* __restrict__ es,
    const float* __restrict__ ed,
    const unsigned short* __restrict__ hb,
    float* __restrict__ agg)
{
    int node = (blockIdx.x * 256 + threadIdx.x) >> 6;
    int lane = threadIdx.x & 63;
    if (node >= N_NODES) return;

    int off = offset[node];
    int deg = count[node];
    float edn = ed[node];

    float2 acc = make_float2(0.f, 0.f);
    float wsum = 0.f;

    #pragma unroll 2
    for (int i = 0; i < deg; ++i) {
        int s = sortedSrc[off + i];
        float a  = es[s] + edn;
        float sg = 1.f / (1.f + __expf(-a));
        float w  = __expf(sg);
        unsigned int u = *(const unsigned int*)(hb + (size_t)s * DHID + 2 * lane);
        acc.x += w * __uint_as_float(u << 16);
        acc.y += w * __uint_as_float(u & 0xffff0000u);
        wsum  += w;
    }
    float inv = (deg > 0) ? 1.f / wsum : 0.f;
    ((float2*)(agg + (size_t)node * DHID))[lane] = make_float2(acc.x * inv, acc.y * inv);
}

// ---------------- h1b = bf16(elu(agg)), 4 elems/thread
__global__ __launch_bounds__(256) void elu_conv_kernel(
    const float* __restrict__ agg, unsigned short* __restrict__ h1b)
{
    int i = (blockIdx.x * 256 + threadIdx.x) * 4;
    float4 v = *(const float4*)(agg + i);
    float e0 = v.x > 0.f ? v.x : (__expf(v.x) - 1.f);
    float e1 = v.y > 0.f ? v.y : (__expf(v.y) - 1.f);
    float e2 = v.z > 0.f ? v.z : (__expf(v.z) - 1.f);
    float e3 = v.w > 0.f ? v.w : (__expf(v.w) - 1.f);
    ushort4 o; o.x = f2b(e0); o.y = f2b(e1); o.z = f2b(e2); o.w = f2b(e3);
    *(ushort4*)(h1b + i) = o;
}

// ---------------- gemm2: out(f32) = h1b @ W2t^T, MFMA, K=128
__global__ __launch_bounds__(256) void gemm2_mfma(
    const unsigned short* __restrict__ h1b,
    const unsigned short* __restrict__ W2t,
    float* __restrict__ out)
{
    const int wave = threadIdx.x >> 6, lane = threadIdx.x & 63;
    const int row0 = blockIdx.x * 64 + wave * 16;
    const int m = lane & 15, q = lane >> 4;

    int r  = row0 + m;
    int rc = (r < N_NODES) ? r : 0;

    f32x4 acc[8];
    #pragma unroll
    for (int t = 0; t < 8; ++t) acc[t] = (f32x4){0.f, 0.f, 0.f, 0.f};

    const short* xp = (const short*)h1b + (size_t)rc * DHID + q * 8;
    const short* wp = (const short*)W2t + q * 8;

    #pragma unroll
    for (int kt = 0; kt < 4; ++kt) {
        bf16x8 a = *(const bf16x8*)(xp + kt * 32);
        #pragma unroll
        for (int t = 0; t < 8; ++t) {
            bf16x8 b = *(const bf16x8*)(wp + (size_t)(t * 16 + m) * DHID + kt * 32);
            acc[t] = __builtin_amdgcn_mfma_f32_16x16x32_bf16(a, b, acc[t], 0, 0, 0);
        }
    }

    #pragma unroll
    for (int reg = 0; reg < 4; ++reg) {
        int rr = row0 + q * 4 + reg;
        if (rr < N_NODES) {
            #pragma unroll
            for (int t = 0; t < 8; ++t)
                out[(size_t)rr * DOUT + t * 16 + m] = acc[t][reg];
        }
    }
}

extern "C" void kernel_launch(void* const* d_in, const int* in_sizes, int n_in,
                              void* d_out, int out_size, void* d_ws, size_t ws_size,
                              hipStream_t stream)
{
    const float* x    = (const float*)d_in[0];
    const int*   ei   = (const int*)d_in[1];
    const float* W1   = (const float*)d_in[2];
    const float* asrc = (const float*)d_in[3];
    const float* adst = (const float*)d_in[4];
    const float* W2   = (const float*)d_in[5];
    float*       out  = (float*)d_out;

    // ---- workspace layout (~43 MB, with overlays) ----
    char* p = (char*)d_ws;
    unsigned short* xb  = (unsigned short*)p;  p += (size_t)N_NODES * DIN * 2;   // 25.6 MB
    unsigned short* hb  = (unsigned short*)p;  p += (size_t)N_NODES * DHID * 2;  // 12.8 MB
    unsigned short* W1t = (unsigned short*)p;  p += (size_t)DHID * DIN * 2;      // 64 KB
    unsigned short* W2t = (unsigned short*)p;  p += (size_t)DOUT * DHID * 2;     // 32 KB
    float* es     = (float*)p;  p += (size_t)N_NODES * 4;
    float* ed     = (float*)p;  p += (size_t)N_NODES * 4;
    int*   count  = (int*)p;    p += (size_t)N_NODES * 4;
    int*   offset = (int*)p;    p += (size_t)N_NODES * 4;
    int*   sortedSrc = (int*)p; p += (size_t)N_EDGES * 4;
    float* agg = (float*)xb;            // overlay: xb dead after gemm1_mfma
    unsigned short* h1b = hb;           // overlay: hb dead after agg_kernel

    hipMemsetAsync(count, 0, sizeof(int) * N_NODES, stream);

    convx_kernel <<<(N_NODES * DIN / 4) / 256, 256, 0, stream>>>(x, xb);
    convW1_kernel<<<(DIN * DHID) / 256,        256, 0, stream>>>(W1, W1t);
    convW2_kernel<<<(DHID * DOUT) / 256,       256, 0, stream>>>(W2, W2t);

    gemm1_mfma<<<(N_NODES + 63) / 64, 256, 0, stream>>>(xb, W1t, hb);
    edot_kernel<<<(N_NODES * 64) / 256 + 1, 256, 0, stream>>>(hb, asrc, adst, es, ed);

    hist_kernel   <<<(N_EDGES + 255) / 256, 256, 0, stream>>>(ei, count);
    scan_kernel   <<<1, 1024, 0, stream>>>(count, offset);
    scatter_kernel<<<(N_EDGES + 255) / 256, 256, 0, stream>>>(ei, offset, count, sortedSrc);

    agg_kernel<<<(N_NODES * 64 + 255) / 256, 256, 0, stream>>>(
        sortedSrc, offset, count, es, ed, hb, agg);

    elu_conv_kernel<<<(N_NODES * DHID / 4) / 256, 256, 0, stream>>>(agg, h1b);
    gemm2_mfma<<<(N_NODES + 63) / 64, 256, 0, stream>>>(h1b, W2t, out);
}

// Round 5
// 312.498 us; speedup vs baseline: 2.9354x; 1.2491x over previous
//
#include <hip/hip_runtime.h>
#include <hip/hip_bf16.h>

#define N_NODES 50000
#define N_EDGES 800000
#define DIN 256
#define DHID 128
#define DOUT 128
#define NBLK 196   // ceil(N_NODES/256)

typedef __attribute__((ext_vector_type(8))) short bf16x8;
typedef __attribute__((ext_vector_type(4))) float f32x4;

__device__ inline unsigned short f2b(float f) {
    __hip_bfloat16 b = __float2bfloat16(f);
    return *reinterpret_cast<unsigned short*>(&b);
}

// ---------------- cast x (f32) -> xb (bf16), 4 elems/thread
__global__ __launch_bounds__(256) void convx_kernel(
    const float* __restrict__ x, unsigned short* __restrict__ xb)
{
    int i = (blockIdx.x * 256 + threadIdx.x) * 4;
    float4 v = *(const float4*)(x + i);
    ushort4 o;
    o.x = f2b(v.x); o.y = f2b(v.y); o.z = f2b(v.z); o.w = f2b(v.w);
    *(ushort4*)(xb + i) = o;
}

// ---------------- transpose+cast both weights in one dispatch
// i < 32768:  W1t[n*256+k] = bf16(W1[k*128+n])
// else:       W2t[n*128+k] = bf16(W2[k*128+n])
__global__ __launch_bounds__(256) void convW_kernel(
    const float* __restrict__ W1, const float* __restrict__ W2,
    unsigned short* __restrict__ W1t, unsigned short* __restrict__ W2t)
{
    int i = blockIdx.x * 256 + threadIdx.x;
    if (i < DIN * DHID) {
        int n = i >> 8, k = i & 255;
        W1t[i] = f2b(W1[k * DHID + n]);
    } else {
        int j = i - DIN * DHID;
        int n = j >> 7, k = j & 127;
        W2t[j] = f2b(W2[k * DOUT + n]);
    }
}

// ---------------- gemm1: hb = bf16( xb @ W1t^T ), MFMA 16x16x32, no LDS.
// Fused epilogue: es = h.att_src, ed = h.att_dst (16-lane shfl_xor reduce).
__global__ __launch_bounds__(256) void gemm1_mfma(
    const unsigned short* __restrict__ xb,
    const unsigned short* __restrict__ W1t,
    const float* __restrict__ att_src,
    const float* __restrict__ att_dst,
    unsigned short* __restrict__ hb,
    float* __restrict__ es,
    float* __restrict__ ed)
{
    const int wave = threadIdx.x >> 6, lane = threadIdx.x & 63;
    const int row0 = blockIdx.x * 64 + wave * 16;
    const int m = lane & 15, q = lane >> 4;

    int r  = row0 + m;
    int rc = (r < N_NODES) ? r : 0;            // clamp; stores guarded below

    f32x4 acc[8];
    #pragma unroll
    for (int t = 0; t < 8; ++t) acc[t] = (f32x4){0.f, 0.f, 0.f, 0.f};

    const short* xp = (const short*)xb + (size_t)rc * DIN + q * 8;
    const short* wp = (const short*)W1t + q * 8;

    #pragma unroll
    for (int kt = 0; kt < 8; ++kt) {
        bf16x8 a = *(const bf16x8*)(xp + kt * 32);
        #pragma unroll
        for (int t = 0; t < 8; ++t) {
            bf16x8 b = *(const bf16x8*)(wp + (size_t)(t * 16 + m) * DIN + kt * 32);
            acc[t] = __builtin_amdgcn_mfma_f32_16x16x32_bf16(a, b, acc[t], 0, 0, 0);
        }
    }

    // C/D layout: row = q*4 + reg, col = t*16 + m
    #pragma unroll
    for (int reg = 0; reg < 4; ++reg) {
        int rr = row0 + q * 4 + reg;
        if (rr < N_NODES) {
            #pragma unroll
            for (int t = 0; t < 8; ++t)
                hb[(size_t)rr * DHID + t * 16 + m] = f2b(acc[t][reg]);
        }
    }

    // fused attention-logit dot products
    float esr[4] = {0.f, 0.f, 0.f, 0.f}, edr[4] = {0.f, 0.f, 0.f, 0.f};
    #pragma unroll
    for (int t = 0; t < 8; ++t) {
        float as = att_src[t * 16 + m];
        float ad = att_dst[t * 16 + m];
        #pragma unroll
        for (int reg = 0; reg < 4; ++reg) {
            esr[reg] += acc[t][reg] * as;
            edr[reg] += acc[t][reg] * ad;
        }
    }
    #pragma unroll
    for (int off = 8; off; off >>= 1)
        #pragma unroll
        for (int reg = 0; reg < 4; ++reg) {
            esr[reg] += __shfl_xor(esr[reg], off);
            edr[reg] += __shfl_xor(edr[reg], off);
        }
    if (m == 0) {
        #pragma unroll
        for (int reg = 0; reg < 4; ++reg) {
            int rr = row0 + q * 4 + reg;
            if (rr < N_NODES) { es[rr] = esr[reg]; ed[rr] = edr[reg]; }
        }
    }
}

// ---------------- histogram of dst degrees
__global__ __launch_bounds__(256) void hist_kernel(
    const int* __restrict__ ei, int* __restrict__ count)
{
    int e = blockIdx.x * 256 + threadIdx.x;
    if (e >= N_EDGES) return;
    atomicAdd(&count[ei[N_EDGES + e]], 1);
}

// ---------------- scan stage A: per-block sums (coalesced)
__global__ __launch_bounds__(256) void blocksum_kernel(
    const int* __restrict__ count, int* __restrict__ blockSums)
{
    __shared__ int ws[4];
    int t = threadIdx.x;
    int i = blockIdx.x * 256 + t;
    int v = (i < N_NODES) ? count[i] : 0;
    #pragma unroll
    for (int off = 32; off; off >>= 1) v += __shfl_down(v, off);
    if ((t & 63) == 0) ws[t >> 6] = v;
    __syncthreads();
    if (t == 0) blockSums[blockIdx.x] = ws[0] + ws[1] + ws[2] + ws[3];
}

// ---------------- scan stage B: exclusive scan of NBLK block sums (1 block)
__global__ __launch_bounds__(256) void scanb_kernel(
    const int* __restrict__ blockSums, int* __restrict__ blockOffsets)
{
    __shared__ int s[256];
    int t = threadIdx.x;
    int v = (t < NBLK) ? blockSums[t] : 0;
    s[t] = v;
    __syncthreads();
    #pragma unroll
    for (int off = 1; off < 256; off <<= 1) {
        int u = (t >= off) ? s[t - off] : 0;
        __syncthreads();
        s[t] += u;
        __syncthreads();
    }
    if (t < NBLK) blockOffsets[t] = s[t] - v;   // exclusive
}

// ---------------- scan stage C: block-local scan + global offset; zero count
__global__ __launch_bounds__(256) void scanc_kernel(
    int* __restrict__ count, const int* __restrict__ blockOffsets,
    int* __restrict__ offset)
{
    __shared__ int s[256];
    int t = threadIdx.x;
    int i = blockIdx.x * 256 + t;
    int c = (i < N_NODES) ? count[i] : 0;
    s[t] = c;
    __syncthreads();
    #pragma unroll
    for (int off = 1; off < 256; off <<= 1) {
        int u = (t >= off) ? s[t - off] : 0;
        __syncthreads();
        s[t] += u;
        __syncthreads();
    }
    if (i < N_NODES) {
        offset[i] = blockOffsets[blockIdx.x] + s[t] - c;   // exclusive prefix
        count[i] = 0;                                      // becomes scatter cursor
    }
}

// ---------------- scatter edge srcs into CSR order
__global__ __launch_bounds__(256) void scatter_kernel(
    const int* __restrict__ ei, const int* __restrict__ offset,
    int* __restrict__ count, int* __restrict__ sortedSrc)
{
    int e = blockIdx.x * 256 + threadIdx.x;
    if (e >= N_EDGES) return;
    int s = ei[e];
    int d = ei[N_EDGES + e];
    int pos = offset[d] + atomicAdd(&count[d], 1);
    sortedSrc[pos] = s;
}

// ---------------- gather-aggregate, one wave per dst node (bf16 h)
__global__ __launch_bounds__(256) void agg_kernel(
    const int* __restrict__ sortedSrc,
    const int* __restrict__ offset,
    const int* __restrict__ count,
    const float* __restrict__ es,
    const float* __restrict__ ed,
    const unsigned short* __restrict__ hb,
    float* __restrict__ agg)
{
    int node = (blockIdx.x * 256 + threadIdx.x) >> 6;
    int lane = threadIdx.x & 63;
    if (node >= N_NODES) return;

    int off = offset[node];
    int deg = count[node];
    float edn = ed[node];

    float2 acc = make_float2(0.f, 0.f);
    float wsum = 0.f;

    #pragma unroll 2
    for (int i = 0; i < deg; ++i) {
        int s = sortedSrc[off + i];
        float a  = es[s] + edn;
        float sg = 1.f / (1.f + __expf(-a));
        float w  = __expf(sg);
        unsigned int u = *(const unsigned int*)(hb + (size_t)s * DHID + 2 * lane);
        acc.x += w * __uint_as_float(u << 16);
        acc.y += w * __uint_as_float(u & 0xffff0000u);
        wsum  += w;
    }
    float inv = (deg > 0) ? 1.f / wsum : 0.f;
    ((float2*)(agg + (size_t)node * DHID))[lane] = make_float2(acc.x * inv, acc.y * inv);
}

// ---------------- h1b = bf16(elu(agg)), 4 elems/thread
__global__ __launch_bounds__(256) void elu_conv_kernel(
    const float* __restrict__ agg, unsigned short* __restrict__ h1b)
{
    int i = (blockIdx.x * 256 + threadIdx.x) * 4;
    float4 v = *(const float4*)(agg + i);
    float e0 = v.x > 0.f ? v.x : (__expf(v.x) - 1.f);
    float e1 = v.y > 0.f ? v.y : (__expf(v.y) - 1.f);
    float e2 = v.z > 0.f ? v.z : (__expf(v.z) - 1.f);
    float e3 = v.w > 0.f ? v.w : (__expf(v.w) - 1.f);
    ushort4 o; o.x = f2b(e0); o.y = f2b(e1); o.z = f2b(e2); o.w = f2b(e3);
    *(ushort4*)(h1b + i) = o;
}

// ---------------- gemm2: out(f32) = h1b @ W2t^T, MFMA, K=128
__global__ __launch_bounds__(256) void gemm2_mfma(
    const unsigned short* __restrict__ h1b,
    const unsigned short* __restrict__ W2t,
    float* __restrict__ out)
{
    const int wave = threadIdx.x >> 6, lane = threadIdx.x & 63;
    const int row0 = blockIdx.x * 64 + wave * 16;
    const int m = lane & 15, q = lane >> 4;

    int r  = row0 + m;
    int rc = (r < N_NODES) ? r : 0;

    f32x4 acc[8];
    #pragma unroll
    for (int t = 0; t < 8; ++t) acc[t] = (f32x4){0.f, 0.f, 0.f, 0.f};

    const short* xp = (const short*)h1b + (size_t)rc * DHID + q * 8;
    const short* wp = (const short*)W2t + q * 8;

    #pragma unroll
    for (int kt = 0; kt < 4; ++kt) {
        bf16x8 a = *(const bf16x8*)(xp + kt * 32);
        #pragma unroll
        for (int t = 0; t < 8; ++t) {
            bf16x8 b = *(const bf16x8*)(wp + (size_t)(t * 16 + m) * DHID + kt * 32);
            acc[t] = __builtin_amdgcn_mfma_f32_16x16x32_bf16(a, b, acc[t], 0, 0, 0);
        }
    }

    #pragma unroll
    for (int reg = 0; reg < 4; ++reg) {
        int rr = row0 + q * 4 + reg;
        if (rr < N_NODES) {
            #pragma unroll
            for (int t = 0; t < 8; ++t)
                out[(size_t)rr * DOUT + t * 16 + m] = acc[t][reg];
        }
    }
}

extern "C" void kernel_launch(void* const* d_in, const int* in_sizes, int n_in,
                              void* d_out, int out_size, void* d_ws, size_t ws_size,
                              hipStream_t stream)
{
    const float* x    = (const float*)d_in[0];
    const int*   ei   = (const int*)d_in[1];
    const float* W1   = (const float*)d_in[2];
    const float* asrc = (const float*)d_in[3];
    const float* adst = (const float*)d_in[4];
    const float* W2   = (const float*)d_in[5];
    float*       out  = (float*)d_out;

    // ---- workspace layout (~43 MB, with overlays) ----
    char* p = (char*)d_ws;
    unsigned short* xb  = (unsigned short*)p;  p += (size_t)N_NODES * DIN * 2;   // 25.6 MB
    unsigned short* hb  = (unsigned short*)p;  p += (size_t)N_NODES * DHID * 2;  // 12.8 MB
    unsigned short* W1t = (unsigned short*)p;  p += (size_t)DHID * DIN * 2;      // 64 KB
    unsigned short* W2t = (unsigned short*)p;  p += (size_t)DOUT * DHID * 2;     // 32 KB
    float* es     = (float*)p;  p += (size_t)N_NODES * 4;
    float* ed     = (float*)p;  p += (size_t)N_NODES * 4;
    int*   count  = (int*)p;    p += (size_t)N_NODES * 4;
    int*   offset = (int*)p;    p += (size_t)N_NODES * 4;
    int*   sortedSrc = (int*)p; p += (size_t)N_EDGES * 4;
    int*   blockSums    = (int*)p; p += 256 * 4;
    int*   blockOffsets = (int*)p; p += 256 * 4;
    float* agg = (float*)xb;            // overlay: xb dead after gemm1_mfma
    unsigned short* h1b = hb;           // overlay: hb dead after agg_kernel

    hipMemsetAsync(count, 0, sizeof(int) * N_NODES, stream);

    convx_kernel<<<(N_NODES * DIN / 4) / 256, 256, 0, stream>>>(x, xb);
    convW_kernel<<<(DIN * DHID + DHID * DOUT) / 256, 256, 0, stream>>>(W1, W2, W1t, W2t);

    gemm1_mfma<<<(N_NODES + 63) / 64, 256, 0, stream>>>(xb, W1t, asrc, adst, hb, es, ed);

    hist_kernel    <<<(N_EDGES + 255) / 256, 256, 0, stream>>>(ei, count);
    blocksum_kernel<<<NBLK, 256, 0, stream>>>(count, blockSums);
    scanb_kernel   <<<1, 256, 0, stream>>>(blockSums, blockOffsets);
    scanc_kernel   <<<NBLK, 256, 0, stream>>>(count, blockOffsets, offset);
    scatter_kernel <<<(N_EDGES + 255) / 256, 256, 0, stream>>>(ei, offset, count, sortedSrc);

    agg_kernel<<<(N_NODES * 64 + 255) / 256, 256, 0, stream>>>(
        sortedSrc, offset, count, es, ed, hb, agg);

    elu_conv_kernel<<<(N_NODES * DHID / 4) / 256, 256, 0, stream>>>(agg, h1b);
    gemm2_mfma<<<(N_NODES + 63) / 64, 256, 0, stream>>>(h1b, W2t, out);
}

// Round 6
// 269.224 us; speedup vs baseline: 3.4073x; 1.1607x over previous
//
#include <hip/hip_runtime.h>
#include <hip/hip_bf16.h>

#define N_NODES 50000
#define N_EDGES 800000
#define DIN 256
#define DHID 128
#define DOUT 128
#define NBLK 196   // ceil(N_NODES/256)

typedef __attribute__((ext_vector_type(8))) short bf16x8;
typedef __attribute__((ext_vector_type(4))) float f32x4;

__device__ inline unsigned short f2b(float f) {
    __hip_bfloat16 b = __float2bfloat16(f);
    return *reinterpret_cast<unsigned short*>(&b);
}

// ---------------- transpose+cast both weights in one dispatch
__global__ __launch_bounds__(256) void convW_kernel(
    const float* __restrict__ W1, const float* __restrict__ W2,
    unsigned short* __restrict__ W1t, unsigned short* __restrict__ W2t)
{
    int i = blockIdx.x * 256 + threadIdx.x;
    if (i < DIN * DHID) {
        int n = i >> 8, k = i & 255;
        W1t[i] = f2b(W1[k * DHID + n]);
    } else {
        int j = i - DIN * DHID;
        int n = j >> 7, k = j & 127;
        W2t[j] = f2b(W2[k * DOUT + n]);
    }
}

// ---------------- gemm1: hb = bf16( bf16(x) @ W1t^T ), MFMA 16x16x32.
// W1t staged in 64KB LDS; x read f32 + converted in-register (convx fused).
// Fused epilogue: es = h.att_src, ed = h.att_dst.
__global__ __launch_bounds__(256) void gemm1_mfma(
    const float* __restrict__ x,
    const unsigned short* __restrict__ W1t,
    const float* __restrict__ att_src,
    const float* __restrict__ att_dst,
    unsigned short* __restrict__ hb,
    float* __restrict__ es,
    float* __restrict__ ed)
{
    __shared__ unsigned short W1s[DHID * DIN];   // 64 KB

    const int tid = threadIdx.x;
    const int wave = tid >> 6, lane = tid & 63;
    const int row0 = blockIdx.x * 64 + wave * 16;
    const int m = lane & 15, q = lane >> 4;

    // stage W1t (coalesced float4 = 8 shorts)
    {
        const float4* src = (const float4*)W1t;
        float4* dst = (float4*)W1s;
        #pragma unroll
        for (int i = 0; i < 16; ++i)
            dst[tid + i * 256] = src[tid + i * 256];
    }
    __syncthreads();

    int r  = row0 + m;
    int rc = (r < N_NODES) ? r : 0;            // clamp; stores guarded below

    f32x4 acc[8];
    #pragma unroll
    for (int t = 0; t < 8; ++t) acc[t] = (f32x4){0.f, 0.f, 0.f, 0.f};

    const float* xr = x + (size_t)rc * DIN + q * 8;
    const short* wp = (const short*)W1s + q * 8;

    #pragma unroll
    for (int kt = 0; kt < 8; ++kt) {
        float4 f0 = *(const float4*)(xr + kt * 32);
        float4 f1 = *(const float4*)(xr + kt * 32 + 4);
        bf16x8 a;
        a[0] = (short)f2b(f0.x); a[1] = (short)f2b(f0.y);
        a[2] = (short)f2b(f0.z); a[3] = (short)f2b(f0.w);
        a[4] = (short)f2b(f1.x); a[5] = (short)f2b(f1.y);
        a[6] = (short)f2b(f1.z); a[7] = (short)f2b(f1.w);
        #pragma unroll
        for (int t = 0; t < 8; ++t) {
            bf16x8 b = *(const bf16x8*)(wp + (t * 16 + m) * DIN + kt * 32);
            acc[t] = __builtin_amdgcn_mfma_f32_16x16x32_bf16(a, b, acc[t], 0, 0, 0);
        }
    }

    // C/D layout: row = q*4 + reg, col = t*16 + m
    #pragma unroll
    for (int reg = 0; reg < 4; ++reg) {
        int rr = row0 + q * 4 + reg;
        if (rr < N_NODES) {
            #pragma unroll
            for (int t = 0; t < 8; ++t)
                hb[(size_t)rr * DHID + t * 16 + m] = f2b(acc[t][reg]);
        }
    }

    // fused attention-logit dot products
    float esr[4] = {0.f, 0.f, 0.f, 0.f}, edr[4] = {0.f, 0.f, 0.f, 0.f};
    #pragma unroll
    for (int t = 0; t < 8; ++t) {
        float as = att_src[t * 16 + m];
        float ad = att_dst[t * 16 + m];
        #pragma unroll
        for (int reg = 0; reg < 4; ++reg) {
            esr[reg] += acc[t][reg] * as;
            edr[reg] += acc[t][reg] * ad;
        }
    }
    #pragma unroll
    for (int off = 8; off; off >>= 1)
        #pragma unroll
        for (int reg = 0; reg < 4; ++reg) {
            esr[reg] += __shfl_xor(esr[reg], off);
            edr[reg] += __shfl_xor(edr[reg], off);
        }
    if (m == 0) {
        #pragma unroll
        for (int reg = 0; reg < 4; ++reg) {
            int rr = row0 + q * 4 + reg;
            if (rr < N_NODES) { es[rr] = esr[reg]; ed[rr] = edr[reg]; }
        }
    }
}

// ---------------- histogram of dst degrees
__global__ __launch_bounds__(256) void hist_kernel(
    const int* __restrict__ ei, int* __restrict__ count)
{
    int e = blockIdx.x * 256 + threadIdx.x;
    if (e >= N_EDGES) return;
    atomicAdd(&count[ei[N_EDGES + e]], 1);
}

// ---------------- scan stage A: per-block sums
__global__ __launch_bounds__(256) void blocksum_kernel(
    const int* __restrict__ count, int* __restrict__ blockSums)
{
    __shared__ int ws[4];
    int t = threadIdx.x;
    int i = blockIdx.x * 256 + t;
    int v = (i < N_NODES) ? count[i] : 0;
    #pragma unroll
    for (int off = 32; off; off >>= 1) v += __shfl_down(v, off);
    if ((t & 63) == 0) ws[t >> 6] = v;
    __syncthreads();
    if (t == 0) blockSums[blockIdx.x] = ws[0] + ws[1] + ws[2] + ws[3];
}

// ---------------- scan stage B: exclusive scan of block sums (1 block)
__global__ __launch_bounds__(256) void scanb_kernel(
    const int* __restrict__ blockSums, int* __restrict__ blockOffsets)
{
    __shared__ int s[256];
    int t = threadIdx.x;
    int v = (t < NBLK) ? blockSums[t] : 0;
    s[t] = v;
    __syncthreads();
    #pragma unroll
    for (int off = 1; off < 256; off <<= 1) {
        int u = (t >= off) ? s[t - off] : 0;
        __syncthreads();
        s[t] += u;
        __syncthreads();
    }
    if (t < NBLK) blockOffsets[t] = s[t] - v;   // exclusive
}

// ---------------- scan stage C: block-local scan + global offset; zero count
__global__ __launch_bounds__(256) void scanc_kernel(
    int* __restrict__ count, const int* __restrict__ blockOffsets,
    int* __restrict__ offset)
{
    __shared__ int s[256];
    int t = threadIdx.x;
    int i = blockIdx.x * 256 + t;
    int c = (i < N_NODES) ? count[i] : 0;
    s[t] = c;
    __syncthreads();
    #pragma unroll
    for (int off = 1; off < 256; off <<= 1) {
        int u = (t >= off) ? s[t - off] : 0;
        __syncthreads();
        s[t] += u;
        __syncthreads();
    }
    if (i < N_NODES) {
        offset[i] = blockOffsets[blockIdx.x] + s[t] - c;   // exclusive prefix
        count[i] = 0;                                      // becomes scatter cursor
    }
}

// ---------------- scatter: compute per-edge w ONCE and scatter {src, w} into CSR order
__global__ __launch_bounds__(256) void scatter_kernel(
    const int* __restrict__ ei,
    const float* __restrict__ es,
    const float* __restrict__ ed,
    const int* __restrict__ offset,
    int* __restrict__ count,
    int2* __restrict__ sortedSW)
{
    int e = blockIdx.x * 256 + threadIdx.x;
    if (e >= N_EDGES) return;
    int s = ei[e];
    int d = ei[N_EDGES + e];
    float a  = es[s] + ed[d];               // es/ed: 200KB each, L2-resident
    float sg = 1.f / (1.f + __expf(-a));
    float w  = __expf(sg);
    int pos = offset[d] + atomicAdd(&count[d], 1);
    sortedSW[pos] = make_int2(s, __float_as_int(w));
}

// ---------------- gather-aggregate, one wave per dst node; w precomputed.
// Chunk-parallel: 64 edges' {s,w} loaded coalesced across lanes, shfl-broadcast.
__global__ __launch_bounds__(256) void agg_kernel(
    const int2* __restrict__ sortedSW,
    const int* __restrict__ offset,
    const int* __restrict__ count,
    const unsigned short* __restrict__ hb,
    float* __restrict__ agg)
{
    int node = (blockIdx.x * 256 + threadIdx.x) >> 6;
    int lane = threadIdx.x & 63;
    if (node >= N_NODES) return;

    int beg = offset[node];
    int deg = count[node];

    float2 acc = make_float2(0.f, 0.f);
    float wsum = 0.f;

    for (int base = 0; base < deg; base += 64) {
        int cnt = min(64, deg - base);
        int2 sw = (lane < cnt) ? sortedSW[beg + base + lane] : make_int2(0, 0);

        // chunk weight sum via butterfly (sw.y is 0 bits -> 0.0f for idle lanes)
        float wl = __uint_as_float((unsigned)sw.y);
        #pragma unroll
        for (int o = 32; o; o >>= 1) wl += __shfl_xor(wl, o);
        wsum += wl;

        for (int j = 0; j < cnt; ++j) {
            int   sj = __shfl(sw.x, j);
            float wj = __uint_as_float((unsigned)__shfl(sw.y, j));
            unsigned int u = *(const unsigned int*)(hb + (size_t)sj * DHID + 2 * lane);
            acc.x += wj * __uint_as_float(u << 16);
            acc.y += wj * __uint_as_float(u & 0xffff0000u);
        }
    }
    float inv = (deg > 0) ? 1.f / wsum : 0.f;
    ((float2*)(agg + (size_t)node * DHID))[lane] = make_float2(acc.x * inv, acc.y * inv);
}

// ---------------- gemm2: out(f32) = bf16(elu(agg)) @ W2t^T, MFMA, K=128.
// W2t staged in 32KB LDS; elu+cvt fused into A-fragment load (elu_conv eliminated).
__global__ __launch_bounds__(256) void gemm2_mfma(
    const float* __restrict__ agg,
    const unsigned short* __restrict__ W2t,
    float* __restrict__ out)
{
    __shared__ unsigned short W2s[DOUT * DHID];   // 32 KB

    const int tid = threadIdx.x;
    const int wave = tid >> 6, lane = tid & 63;
    const int row0 = blockIdx.x * 64 + wave * 16;
    const int m = lane & 15, q = lane >> 4;

    {
        const float4* src = (const float4*)W2t;
        float4* dst = (float4*)W2s;
        #pragma unroll
        for (int i = 0; i < 8; ++i)
            dst[tid + i * 256] = src[tid + i * 256];
    }
    __syncthreads();

    int r  = row0 + m;
    int rc = (r < N_NODES) ? r : 0;

    f32x4 acc[8];
    #pragma unroll
    for (int t = 0; t < 8; ++t) acc[t] = (f32x4){0.f, 0.f, 0.f, 0.f};

    const float* ar = agg + (size_t)rc * DHID + q * 8;
    const short* wp = (const short*)W2s + q * 8;

    #pragma unroll
    for (int kt = 0; kt < 4; ++kt) {
        float4 f0 = *(const float4*)(ar + kt * 32);
        float4 f1 = *(const float4*)(ar + kt * 32 + 4);
        float e0 = f0.x > 0.f ? f0.x : (__expf(f0.x) - 1.f);
        float e1 = f0.y > 0.f ? f0.y : (__expf(f0.y) - 1.f);
        float e2 = f0.z > 0.f ? f0.z : (__expf(f0.z) - 1.f);
        float e3 = f0.w > 0.f ? f0.w : (__expf(f0.w) - 1.f);
        float e4 = f1.x > 0.f ? f1.x : (__expf(f1.x) - 1.f);
        float e5 = f1.y > 0.f ? f1.y : (__expf(f1.y) - 1.f);
        float e6 = f1.z > 0.f ? f1.z : (__expf(f1.z) - 1.f);
        float e7 = f1.w > 0.f ? f1.w : (__expf(f1.w) - 1.f);
        bf16x8 a;
        a[0] = (short)f2b(e0); a[1] = (short)f2b(e1);
        a[2] = (short)f2b(e2); a[3] = (short)f2b(e3);
        a[4] = (short)f2b(e4); a[5] = (short)f2b(e5);
        a[6] = (short)f2b(e6); a[7] = (short)f2b(e7);
        #pragma unroll
        for (int t = 0; t < 8; ++t) {
            bf16x8 b = *(const bf16x8*)(wp + (t * 16 + m) * DHID + kt * 32);
            acc[t] = __builtin_amdgcn_mfma_f32_16x16x32_bf16(a, b, acc[t], 0, 0, 0);
        }
    }

    #pragma unroll
    for (int reg = 0; reg < 4; ++reg) {
        int rr = row0 + q * 4 + reg;
        if (rr < N_NODES) {
            #pragma unroll
            for (int t = 0; t < 8; ++t)
                out[(size_t)rr * DOUT + t * 16 + m] = acc[t][reg];
        }
    }
}

extern "C" void kernel_launch(void* const* d_in, const int* in_sizes, int n_in,
                              void* d_out, int out_size, void* d_ws, size_t ws_size,
                              hipStream_t stream)
{
    const float* x    = (const float*)d_in[0];
    const int*   ei   = (const int*)d_in[1];
    const float* W1   = (const float*)d_in[2];
    const float* asrc = (const float*)d_in[3];
    const float* adst = (const float*)d_in[4];
    const float* W2   = (const float*)d_in[5];
    float*       out  = (float*)d_out;

    // ---- workspace layout (~46 MB) ----
    char* p = (char*)d_ws;
    unsigned short* hb  = (unsigned short*)p;  p += (size_t)N_NODES * DHID * 2;  // 12.8 MB
    unsigned short* W1t = (unsigned short*)p;  p += (size_t)DHID * DIN * 2;      // 64 KB
    unsigned short* W2t = (unsigned short*)p;  p += (size_t)DOUT * DHID * 2;     // 32 KB
    float* es     = (float*)p;  p += (size_t)N_NODES * 4;
    float* ed     = (float*)p;  p += (size_t)N_NODES * 4;
    int*   count  = (int*)p;    p += (size_t)N_NODES * 4;
    int*   offset = (int*)p;    p += (size_t)N_NODES * 4;
    int*   blockSums    = (int*)p; p += 256 * 4;
    int*   blockOffsets = (int*)p; p += 256 * 4;
    int2*  sortedSW = (int2*)p; p += (size_t)N_EDGES * 8;                        // 6.4 MB
    float* agg      = (float*)p;                                                 // 25.6 MB

    hipMemsetAsync(count, 0, sizeof(int) * N_NODES, stream);

    convW_kernel<<<(DIN * DHID + DHID * DOUT) / 256, 256, 0, stream>>>(W1, W2, W1t, W2t);

    gemm1_mfma<<<(N_NODES + 63) / 64, 256, 0, stream>>>(x, W1t, asrc, adst, hb, es, ed);

    hist_kernel    <<<(N_EDGES + 255) / 256, 256, 0, stream>>>(ei, count);
    blocksum_kernel<<<NBLK, 256, 0, stream>>>(count, blockSums);
    scanb_kernel   <<<1, 256, 0, stream>>>(blockSums, blockOffsets);
    scanc_kernel   <<<NBLK, 256, 0, stream>>>(count, blockOffsets, offset);
    scatter_kernel <<<(N_EDGES + 255) / 256, 256, 0, stream>>>(
        ei, es, ed, offset, count, sortedSW);

    agg_kernel<<<(N_NODES * 64 + 255) / 256, 256, 0, stream>>>(
        sortedSW, offset, count, hb, agg);

    gemm2_mfma<<<(N_NODES + 63) / 64, 256, 0, stream>>>(agg, W2t, out);
}